// Round 5
// baseline (298.652 us; speedup 1.0000x reference)
//
#include <hip/hip_runtime.h>
#include <math.h>

// Problem constants (B=64, C=128, H=W=56)
#define HW 3136
#define NCH224 896           // 64 batches * 14 chunks of 224 samples
#define M_TOT 200704.0f
#define EPSV 1e-5f

typedef __attribute__((ext_vector_type(8))) short bf16x8;
typedef __attribute__((ext_vector_type(4))) short short4v;
typedef __attribute__((ext_vector_type(4))) float f32x4;

__device__ inline unsigned short f2bf(float f) {  // RNE fp32->bf16
  unsigned u = __float_as_uint(f);
  u += 0x7FFFu + ((u >> 16) & 1u);
  return (unsigned short)(u >> 16);
}

// ---------------------------------------------------------------------------
// Kernel 1: partial Gram (X @ X^T) + channel sums, bf16 MFMA 16x16x32.
// Round-5: keep the 224-sample chunk (r4: 2.45 TB/s vs 1.0 at 64 samples)
// but cut partG volume: slots = 448 (2 chunks accumulated per block; exactly
// fills 2-blocks/CU residency, no tail) and write ONLY upper-triangle tiles
// (tj >= w): per-slot partial Grams are bit-exactly symmetric, so the lower
// half is redundant. partG write 58.7 -> 16.1 MB.
// D layout (m89): col = lane&15, row = quad*4 + reg.
// ---------------------------------------------------------------------------
__global__ __launch_bounds__(512, 4) void gram_k(const float* __restrict__ x,
                                                 float* __restrict__ partG,
                                                 float* __restrict__ partS,
                                                 int slots) {
  __shared__ unsigned short xs[128 * 232];  // 59392 B
  const int t = threadIdx.x;
  const int lm = t & 15, quad = (t >> 4) & 3, w = t >> 6;  // w = 0..7
  const int row0 = w * 16;

  f32x4 acc[8];
  f32x4 sacc;
  const f32x4 z = {0.f, 0.f, 0.f, 0.f};
  sacc = z;
#pragma unroll
  for (int j = 0; j < 8; ++j) acc[j] = z;
  bf16x8 ones;
#pragma unroll
  for (int j = 0; j < 8; ++j) ones[j] = (short)0x3F80;  // bf16 1.0

  for (int chunk = blockIdx.x; chunk < NCH224; chunk += slots) {
    const int b = chunk / 14;
    const int s0 = (chunk % 14) * 224;
    const float* base = x + (size_t)(b * 128) * HW + s0;

    // phase 1: issue ALL loads (14 float4/thread, 896B contiguous channel rows)
    float4 buf[14];
#pragma unroll
    for (int i = 0; i < 14; ++i) {
      const int id = t + i * 512;      // 0..7167
      const int c = id / 56;           // channel (56 quads per 224-sample row)
      const int qi = id - c * 56;
      buf[i] = *(const float4*)(base + (size_t)c * HW + 4 * qi);
    }
    // phase 2: convert + stage to LDS
#pragma unroll
    for (int i = 0; i < 14; ++i) {
      const int id = t + i * 512;
      const int c = id / 56;
      const int qi = id - c * 56;
      uint2 dw;
      dw.x = (unsigned)f2bf(buf[i].x) | ((unsigned)f2bf(buf[i].y) << 16);
      dw.y = (unsigned)f2bf(buf[i].z) | ((unsigned)f2bf(buf[i].w) << 16);
      *(uint2*)&xs[c * 232 + 4 * qi] = dw;
    }
    __syncthreads();

    // compute: 7 k-steps of 32 samples, 9 MFMA each (8 G-tiles + ones-rowsum)
#pragma unroll
    for (int ks = 0; ks < 7; ++ks) {
      const int ko = ks * 32 + quad * 8;
      const bf16x8 a0 = *(const bf16x8*)&xs[(row0 + lm) * 232 + ko];
      sacc = __builtin_amdgcn_mfma_f32_16x16x32_bf16(a0, ones, sacc, 0, 0, 0);
#pragma unroll
      for (int tj = 0; tj < 8; ++tj) {
        const bf16x8 bf = *(const bf16x8*)&xs[(tj * 16 + lm) * 232 + ko];
        acc[tj] = __builtin_amdgcn_mfma_f32_16x16x32_bf16(a0, bf, acc[tj], 0, 0, 0);
      }
    }
    __syncthreads();  // protect xs before next staging
  }

  // epilogue: upper-triangle tiles only (tj >= w)
  float* pg = partG + (size_t)blockIdx.x * 16384;
#pragma unroll
  for (int tj = 0; tj < 8; ++tj) {
    if (tj >= w) {
#pragma unroll
      for (int r = 0; r < 4; ++r)
        pg[(row0 + quad * 4 + r) * 128 + tj * 16 + lm] = acc[tj][r];
    }
  }
  if (lm == 0) {
#pragma unroll
    for (int r = 0; r < 4; ++r)
      partS[blockIdx.x * 128 + row0 + quad * 4 + r] = sacc[r];
  }
}

// ---------------------------------------------------------------------------
// Kernel 2: stage-A reduction over UPPER-TRIANGLE tiles only.
// grid = 32 slot-groups x 9 tile-groups = 288 blocks; each tile-group owns
// 4 of the 36 upper tiles; each thread reduces one float4 position across
// its slot-group (stride 32). part2 keeps the same 128x128 slot layout
// (lower tiles left unwritten -- never read).
// ---------------------------------------------------------------------------
__global__ __launch_bounds__(256) void reduce1_k(const float* __restrict__ partG,
                                                 const float* __restrict__ partS,
                                                 float* __restrict__ part2,
                                                 float* __restrict__ part2S,
                                                 int slots) {
  const int t = threadIdx.x;
  const int sg = blockIdx.x & 31;
  const int tg = blockIdx.x >> 5;          // 0..8
  const int ti = tg * 4 + (t >> 6);        // upper-tile index 0..35 (wave-uniform)
  int tr = 0, rem = ti;
  while (rem >= 8 - tr) { rem -= 8 - tr; ++tr; }
  const int tc = tr + rem;
  const int f = t & 63;                    // float4 slot within tile
  const int rr = f >> 2, c4 = f & 3;
  const int off = (tr * 16 + rr) * 128 + tc * 16 + c4 * 4;

  float ax = 0.f, ay = 0.f, az = 0.f, aw = 0.f;
#pragma unroll 4
  for (int s = sg; s < slots; s += 32) {
    const float4 v = *(const float4*)(partG + (size_t)s * 16384 + off);
    ax += v.x; ay += v.y; az += v.z; aw += v.w;
  }
  *(float4*)(part2 + (size_t)sg * 16384 + off) = make_float4(ax, ay, az, aw);
  if (tg == 0 && t < 128) {
    float sa = 0.f;
    for (int s = sg; s < slots; s += 32) sa += partS[s * 128 + t];
    part2S[sg * 128 + t] = sa;
  }
}

// ---------------------------------------------------------------------------
// Kernel 3: merged stage-B reduce + Sigma build. grid = 16, block = 256.
// Lower-triangle tiles are mirrored from the (bit-identical) upper partials
// via strided scalar gathers. Raw Sigma = (G - S S^T/m)/m + eps*I.
// ---------------------------------------------------------------------------
__global__ __launch_bounds__(256) void sigred_k(const float* __restrict__ part2,
                                                const float* __restrict__ part2S,
                                                float* __restrict__ Sigma,
                                                float* __restrict__ traceP,
                                                float* __restrict__ meanOut) {
  __shared__ float SbL[128];
  __shared__ float red[256];
  const int t = threadIdx.x;
  if (t < 128) {
    float sa = 0.f;
#pragma unroll
    for (int sg = 0; sg < 32; ++sg) sa += part2S[sg * 128 + t];
    SbL[t] = sa;
    if (blockIdx.x == 0) meanOut[t] = sa * (1.0f / M_TOT);
  }
  __syncthreads();
  const int e4 = blockIdx.x * 1024 + t * 4;
  const int r = e4 >> 7, c0 = e4 & 127;
  const int tr = r >> 4, tc = c0 >> 4;
  float ax = 0.f, ay = 0.f, az = 0.f, aw = 0.f;
  if (tc >= tr) {
#pragma unroll
    for (int sg = 0; sg < 32; ++sg) {
      const float4 v = *(const float4*)(part2 + (size_t)sg * 16384 + e4);
      ax += v.x; ay += v.y; az += v.z; aw += v.w;
    }
  } else {
    // mirrored: element (r, c0+j) <- upper element (c0+j, r)
#pragma unroll
    for (int sg = 0; sg < 32; ++sg) {
      const float* p = part2 + (size_t)sg * 16384 + r;
      ax += p[(c0 + 0) * 128];
      ay += p[(c0 + 1) * 128];
      az += p[(c0 + 2) * 128];
      aw += p[(c0 + 3) * 128];
    }
  }
  const float rm = 1.0f / M_TOT;
  const float sr = SbL[r] * rm;
  float s4[4];
  s4[0] = (ax - sr * SbL[c0 + 0]) * rm;
  s4[1] = (ay - sr * SbL[c0 + 1]) * rm;
  s4[2] = (az - sr * SbL[c0 + 2]) * rm;
  s4[3] = (aw - sr * SbL[c0 + 3]) * rm;
  float trl = 0.f;
#pragma unroll
  for (int j = 0; j < 4; ++j) {
    if (c0 + j == r) { s4[j] += EPSV; trl = s4[j]; }
  }
  *(float4*)(Sigma + e4) = make_float4(s4[0], s4[1], s4[2], s4[3]);
  red[t] = trl;
  __syncthreads();
  for (int off = 128; off > 0; off >>= 1) {
    if (t < off) red[t] += red[t + off];
    __syncthreads();
  }
  if (t == 0) traceP[blockIdx.x] = red[0];
}

// ---------------------------------------------------------------------------
// Kernel 4a: FIRST+SECOND Newton step fused (P1 = 1.5I - 0.5*rTr*Sigma
// synthesized; computes P2). grid = 16, block = 256. 4x4 tile, 4-way K-split.
// ---------------------------------------------------------------------------
__global__ __launch_bounds__(256) void newton1_k(const float* __restrict__ Sig,
                                                 const float* __restrict__ traceP,
                                                 float* __restrict__ Pout) {
  __shared__ float s1[8 * 132];
  __shared__ float s2[8 * 132];
  __shared__ float red[256 * 17];
  const int t = threadIdx.x;
  const int ct = t & 31;
  const int rt = (t >> 5) & 1;
  const int kt = t >> 6;
  const int rg0 = blockIdx.x * 8;
  const int ra = rg0 + 4 * rt;
  float tr = 0.f;
#pragma unroll
  for (int i = 0; i < 16; ++i) tr += traceP[i];
  const float rTr = 1.0f / tr;
  const float nh = -0.5f * rTr;
  float a[4][4];

  // ---------- phase 1: s1 = strip(P1 @ P1) ----------
#pragma unroll
  for (int i = 0; i < 4; ++i)
#pragma unroll
    for (int j = 0; j < 4; ++j) a[i][j] = 0.f;
#pragma unroll 4
  for (int k = kt * 32; k < kt * 32 + 32; ++k) {
    const float4 sa4 = *(const float4*)(Sig + k * 128 + ra);   // symmetry
    const float4 sb4 = *(const float4*)(Sig + k * 128 + 4 * ct);
    float aA[4] = {nh * sa4.x, nh * sa4.y, nh * sa4.z, nh * sa4.w};
    float bA[4] = {nh * sb4.x, nh * sb4.y, nh * sb4.z, nh * sb4.w};
#pragma unroll
    for (int i = 0; i < 4; ++i) if (ra + i == k) aA[i] += 1.5f;
#pragma unroll
    for (int j = 0; j < 4; ++j) if (4 * ct + j == k) bA[j] += 1.5f;
#pragma unroll
    for (int i = 0; i < 4; ++i)
#pragma unroll
      for (int j = 0; j < 4; ++j) a[i][j] += aA[i] * bA[j];
  }
#pragma unroll
  for (int i = 0; i < 4; ++i)
#pragma unroll
    for (int j = 0; j < 4; ++j) red[t * 17 + i * 4 + j] = a[i][j];
  __syncthreads();
  if (t < 64) {
#pragma unroll
    for (int u = 1; u < 4; ++u)
#pragma unroll
      for (int i = 0; i < 4; ++i)
#pragma unroll
        for (int j = 0; j < 4; ++j)
          a[i][j] += red[(t + 64 * u) * 17 + i * 4 + j];
#pragma unroll
    for (int i = 0; i < 4; ++i)
#pragma unroll
      for (int j = 0; j < 4; ++j)
        s1[(4 * rt + i) * 132 + 4 * ct + j] = a[i][j];
  }
  __syncthreads();

  // ---------- phase 2: s2 = s1 @ P1 ----------
#pragma unroll
  for (int i = 0; i < 4; ++i)
#pragma unroll
    for (int j = 0; j < 4; ++j) a[i][j] = 0.f;
#pragma unroll 4
  for (int k = kt * 32; k < kt * 32 + 32; ++k) {
    float aA[4];
#pragma unroll
    for (int i = 0; i < 4; ++i) aA[i] = s1[(4 * rt + i) * 132 + k];
    const float4 sb4 = *(const float4*)(Sig + k * 128 + 4 * ct);
    float bA[4] = {nh * sb4.x, nh * sb4.y, nh * sb4.z, nh * sb4.w};
#pragma unroll
    for (int j = 0; j < 4; ++j) if (4 * ct + j == k) bA[j] += 1.5f;
#pragma unroll
    for (int i = 0; i < 4; ++i)
#pragma unroll
      for (int j = 0; j < 4; ++j) a[i][j] += aA[i] * bA[j];
  }
  __syncthreads();
#pragma unroll
  for (int i = 0; i < 4; ++i)
#pragma unroll
    for (int j = 0; j < 4; ++j) red[t * 17 + i * 4 + j] = a[i][j];
  __syncthreads();
  if (t < 64) {
#pragma unroll
    for (int u = 1; u < 4; ++u)
#pragma unroll
      for (int i = 0; i < 4; ++i)
#pragma unroll
        for (int j = 0; j < 4; ++j)
          a[i][j] += red[(t + 64 * u) * 17 + i * 4 + j];
#pragma unroll
    for (int i = 0; i < 4; ++i)
#pragma unroll
      for (int j = 0; j < 4; ++j)
        s2[(4 * rt + i) * 132 + 4 * ct + j] = a[i][j];
  }
  __syncthreads();

  // ---------- phase 3: a = s2 @ Sigma_raw; Pout = 0.5*(3 P1 - rTr*a) ----------
#pragma unroll
  for (int i = 0; i < 4; ++i)
#pragma unroll
    for (int j = 0; j < 4; ++j) a[i][j] = 0.f;
#pragma unroll 4
  for (int k = kt * 32; k < kt * 32 + 32; ++k) {
    float aA[4];
#pragma unroll
    for (int i = 0; i < 4; ++i) aA[i] = s2[(4 * rt + i) * 132 + k];
    const float4 bv = *(const float4*)(Sig + k * 128 + 4 * ct);
    const float bA[4] = {bv.x, bv.y, bv.z, bv.w};
#pragma unroll
    for (int i = 0; i < 4; ++i)
#pragma unroll
      for (int j = 0; j < 4; ++j) a[i][j] += aA[i] * bA[j];
  }
  __syncthreads();
#pragma unroll
  for (int i = 0; i < 4; ++i)
#pragma unroll
    for (int j = 0; j < 4; ++j) red[t * 17 + i * 4 + j] = a[i][j];
  __syncthreads();
  if (t < 64) {
#pragma unroll
    for (int u = 1; u < 4; ++u)
#pragma unroll
      for (int i = 0; i < 4; ++i)
#pragma unroll
        for (int j = 0; j < 4; ++j)
          a[i][j] += red[(t + 64 * u) * 17 + i * 4 + j];
#pragma unroll
    for (int i = 0; i < 4; ++i) {
      const int rg = rg0 + 4 * rt + i;
      const float4 sv = *(const float4*)(Sig + rg * 128 + 4 * ct);
      float p1v[4] = {nh * sv.x, nh * sv.y, nh * sv.z, nh * sv.w};
#pragma unroll
      for (int j = 0; j < 4; ++j) if (4 * ct + j == rg) p1v[j] += 1.5f;
      *(float4*)(Pout + rg * 128 + 4 * ct) =
          make_float4(0.5f * (3.f * p1v[0] - rTr * a[i][0]),
                      0.5f * (3.f * p1v[1] - rTr * a[i][1]),
                      0.5f * (3.f * p1v[2] - rTr * a[i][2]),
                      0.5f * (3.f * p1v[3] - rTr * a[i][3]));
    }
  }
}

// ---------------------------------------------------------------------------
// Kernel 4b: one Newton iteration: Pout = 0.5*(3P - ((P@P)@P)@(rTr*Sigma)).
// grid = 16, block = 256. P from global (symmetric).
// ---------------------------------------------------------------------------
__global__ __launch_bounds__(256) void newton_k(const float* __restrict__ P,
                                                const float* __restrict__ Sig,
                                                const float* __restrict__ traceP,
                                                float* __restrict__ Pout) {
  __shared__ float s1[8 * 132];
  __shared__ float s2[8 * 132];
  __shared__ float red[256 * 17];
  const int t = threadIdx.x;
  const int ct = t & 31;
  const int rt = (t >> 5) & 1;
  const int kt = t >> 6;
  const int rg0 = blockIdx.x * 8;
  float tr = 0.f;
#pragma unroll
  for (int i = 0; i < 16; ++i) tr += traceP[i];
  const float rTr = 1.0f / tr;
  float a[4][4];

  // ---------- phase 1: s1 = strip(P @ P) ----------
#pragma unroll
  for (int i = 0; i < 4; ++i)
#pragma unroll
    for (int j = 0; j < 4; ++j) a[i][j] = 0.f;
#pragma unroll 4
  for (int k = kt * 32; k < kt * 32 + 32; ++k) {
    const float4 av = *(const float4*)(P + k * 128 + rg0 + 4 * rt);  // symmetry
    const float4 bv = *(const float4*)(P + k * 128 + 4 * ct);
    const float aA[4] = {av.x, av.y, av.z, av.w};
    const float bA[4] = {bv.x, bv.y, bv.z, bv.w};
#pragma unroll
    for (int i = 0; i < 4; ++i)
#pragma unroll
      for (int j = 0; j < 4; ++j) a[i][j] += aA[i] * bA[j];
  }
#pragma unroll
  for (int i = 0; i < 4; ++i)
#pragma unroll
    for (int j = 0; j < 4; ++j) red[t * 17 + i * 4 + j] = a[i][j];
  __syncthreads();
  if (t < 64) {
#pragma unroll
    for (int u = 1; u < 4; ++u)
#pragma unroll
      for (int i = 0; i < 4; ++i)
#pragma unroll
        for (int j = 0; j < 4; ++j)
          a[i][j] += red[(t + 64 * u) * 17 + i * 4 + j];
#pragma unroll
    for (int i = 0; i < 4; ++i)
#pragma unroll
      for (int j = 0; j < 4; ++j)
        s1[(4 * rt + i) * 132 + 4 * ct + j] = a[i][j];
  }
  __syncthreads();

  // ---------- phase 2: s2 = s1 @ P ----------
#pragma unroll
  for (int i = 0; i < 4; ++i)
#pragma unroll
    for (int j = 0; j < 4; ++j) a[i][j] = 0.f;
#pragma unroll 4
  for (int k = kt * 32; k < kt * 32 + 32; ++k) {
    float aA[4];
#pragma unroll
    for (int i = 0; i < 4; ++i) aA[i] = s1[(4 * rt + i) * 132 + k];
    const float4 bv = *(const float4*)(P + k * 128 + 4 * ct);
    const float bA[4] = {bv.x, bv.y, bv.z, bv.w};
#pragma unroll
    for (int i = 0; i < 4; ++i)
#pragma unroll
      for (int j = 0; j < 4; ++j) a[i][j] += aA[i] * bA[j];
  }
  __syncthreads();
#pragma unroll
  for (int i = 0; i < 4; ++i)
#pragma unroll
    for (int j = 0; j < 4; ++j) red[t * 17 + i * 4 + j] = a[i][j];
  __syncthreads();
  if (t < 64) {
#pragma unroll
    for (int u = 1; u < 4; ++u)
#pragma unroll
      for (int i = 0; i < 4; ++i)
#pragma unroll
        for (int j = 0; j < 4; ++j)
          a[i][j] += red[(t + 64 * u) * 17 + i * 4 + j];
#pragma unroll
    for (int i = 0; i < 4; ++i)
#pragma unroll
      for (int j = 0; j < 4; ++j)
        s2[(4 * rt + i) * 132 + 4 * ct + j] = a[i][j];
  }
  __syncthreads();

  // ---------- phase 3: a = s2 @ Sigma_raw; Pout = 0.5*(3P - rTr*a) ----------
#pragma unroll
  for (int i = 0; i < 4; ++i)
#pragma unroll
    for (int j = 0; j < 4; ++j) a[i][j] = 0.f;
#pragma unroll 4
  for (int k = kt * 32; k < kt * 32 + 32; ++k) {
    float aA[4];
#pragma unroll
    for (int i = 0; i < 4; ++i) aA[i] = s2[(4 * rt + i) * 132 + k];
    const float4 bv = *(const float4*)(Sig + k * 128 + 4 * ct);
    const float bA[4] = {bv.x, bv.y, bv.z, bv.w};
#pragma unroll
    for (int i = 0; i < 4; ++i)
#pragma unroll
      for (int j = 0; j < 4; ++j) a[i][j] += aA[i] * bA[j];
  }
  __syncthreads();
#pragma unroll
  for (int i = 0; i < 4; ++i)
#pragma unroll
    for (int j = 0; j < 4; ++j) red[t * 17 + i * 4 + j] = a[i][j];
  __syncthreads();
  if (t < 64) {
#pragma unroll
    for (int u = 1; u < 4; ++u)
#pragma unroll
      for (int i = 0; i < 4; ++i)
#pragma unroll
        for (int j = 0; j < 4; ++j)
          a[i][j] += red[(t + 64 * u) * 17 + i * 4 + j];
#pragma unroll
    for (int i = 0; i < 4; ++i) {
      const int rg = rg0 + 4 * rt + i;
      const float4 pv = *(const float4*)(P + rg * 128 + 4 * ct);
      *(float4*)(Pout + rg * 128 + 4 * ct) =
          make_float4(0.5f * (3.f * pv.x - rTr * a[i][0]),
                      0.5f * (3.f * pv.y - rTr * a[i][1]),
                      0.5f * (3.f * pv.z - rTr * a[i][2]),
                      0.5f * (3.f * pv.w - rTr * a[i][3]));
    }
  }
}

// ---------------------------------------------------------------------------
// Kernel 5: Mbf = bf16(sqrt(rTr) * rot @ P) row-major [d][c];
// bias[d] = sum_c M[d][c]*mean[c]. grid = 16, block = 256.
// ---------------------------------------------------------------------------
__global__ __launch_bounds__(256) void rotmt_k(const float* __restrict__ rot,
                                               const float* __restrict__ P,
                                               const float* __restrict__ mean,
                                               const float* __restrict__ traceP,
                                               unsigned short* __restrict__ Mbf,
                                               float* __restrict__ bias) {
  const int t = threadIdx.x;
  const int r = t >> 5;
  const int dg = blockIdx.x * 8 + r;
  const int c0 = (t & 31) * 4;
  const float* rrow = rot + dg * 128;
  float tr = 0.f;
#pragma unroll
  for (int i = 0; i < 16; ++i) tr += traceP[i];
  const float sc = sqrtf(1.0f / tr);

  float ax = 0, ay = 0, az = 0, aw = 0;
#pragma unroll 4
  for (int k = 0; k < 128; ++k) {
    const float a = rrow[k];
    const float4 bv = *(const float4*)(P + k * 128 + c0);
    ax += a * bv.x; ay += a * bv.y; az += a * bv.z; aw += a * bv.w;
  }
  ax *= sc; ay *= sc; az *= sc; aw *= sc;
  uint2 dw;
  dw.x = (unsigned)f2bf(ax) | ((unsigned)f2bf(ay) << 16);
  dw.y = (unsigned)f2bf(az) | ((unsigned)f2bf(aw) << 16);
  *(uint2*)&Mbf[dg * 128 + c0] = dw;
  const float4 mv = *(const float4*)(mean + c0);
  float p = ax * mv.x + ay * mv.y + az * mv.z + aw * mv.w;
  for (int off = 16; off > 0; off >>= 1) p += __shfl_down(p, off, 32);
  if ((t & 31) == 0) bias[dg] = p;
}

// ---------------------------------------------------------------------------
// Kernel 6: out[b,d,s] = sum_c M[d][c]*x[c,s] - bias[d], bf16 MFMA.
// grid = 3136, block = 256 (4 waves), 3 blocks/CU (LDS 51.7KB x3 = 155KB).
// ---------------------------------------------------------------------------
#define MSTR 136
#define XSTR 132
__global__ __launch_bounds__(256, 3) void apply_k(const float* __restrict__ x,
                                                  const unsigned short* __restrict__ Mbf,
                                                  const float* __restrict__ bias,
                                                  float* __restrict__ out) {
  __shared__ unsigned short Ms[128 * MSTR];   // 34816 B
  __shared__ unsigned short xsB[64 * XSTR];   // 16896 B
  const int t = threadIdx.x;
  const int lm = t & 15, quad = (t >> 4) & 3, w = t >> 6;
  const int b = blockIdx.x / 49;
  const int s0 = (blockIdx.x % 49) * 64;

  // stage M (L2-hot) -- independent of x loads, overlaps them
#pragma unroll
  for (int i = 0; i < 8; ++i) {
    const int e = i * 256 + t;
    const int row = e >> 4, oct = e & 15;
    *(uint4*)&Ms[row * MSTR + oct * 8] =
        *(const uint4*)(Mbf + row * 128 + oct * 8);
  }
  // stage x chunk transposed: pair p -> channels {2p, 2p+1}
#pragma unroll
  for (int i = 0; i < 4; ++i) {
    const int p = 16 * i + (t >> 4);
    const int q = t & 15;
    const float* px = x + (size_t)(b * 128 + 2 * p) * HW + s0 + 4 * q;
    const float4 fa = *(const float4*)px;
    const float4 fb = *(const float4*)(px + HW);
    const float faA[4] = {fa.x, fa.y, fa.z, fa.w};
    const float fbA[4] = {fb.x, fb.y, fb.z, fb.w};
#pragma unroll
    for (int r = 0; r < 4; ++r) {
      const unsigned dw =
          (unsigned)f2bf(faA[r]) | ((unsigned)f2bf(fbA[r]) << 16);
      *(unsigned*)&xsB[(4 * q + r) * XSTR + 2 * p] = dw;
    }
  }
  float biasr[2][4];
#pragma unroll
  for (int i = 0; i < 2; ++i)
#pragma unroll
    for (int r = 0; r < 4; ++r)
      biasr[i][r] = bias[(2 * w + i) * 16 + quad * 4 + r];
  __syncthreads();

  const f32x4 z = {0.f, 0.f, 0.f, 0.f};
  f32x4 acc[2][4];
#pragma unroll
  for (int i = 0; i < 2; ++i)
#pragma unroll
    for (int sj = 0; sj < 4; ++sj) acc[i][sj] = z;

#pragma unroll
  for (int ks = 0; ks < 4; ++ks) {
    const int ko = ks * 32 + quad * 8;
    const bf16x8 a0 = *(const bf16x8*)&Ms[((2 * w + 0) * 16 + lm) * MSTR + ko];
    const bf16x8 a1 = *(const bf16x8*)&Ms[((2 * w + 1) * 16 + lm) * MSTR + ko];
#pragma unroll
    for (int sj = 0; sj < 4; ++sj) {
      const short4v blo = *(const short4v*)&xsB[(sj * 16 + lm) * XSTR + ko];
      const short4v bhi = *(const short4v*)&xsB[(sj * 16 + lm) * XSTR + ko + 4];
      const bf16x8 bf = __builtin_shufflevector(blo, bhi, 0, 1, 2, 3, 4, 5, 6, 7);
      acc[0][sj] = __builtin_amdgcn_mfma_f32_16x16x32_bf16(a0, bf, acc[0][sj], 0, 0, 0);
      acc[1][sj] = __builtin_amdgcn_mfma_f32_16x16x32_bf16(a1, bf, acc[1][sj], 0, 0, 0);
    }
  }
  // epilogue: D col = lane&15 = s, row = quad*4+reg = d-within-tile
#pragma unroll
  for (int i = 0; i < 2; ++i)
#pragma unroll
    for (int r = 0; r < 4; ++r) {
      const int d = (2 * w + i) * 16 + quad * 4 + r;
      float* orow = out + (size_t)(b * 128 + d) * HW + s0 + lm;
#pragma unroll
      for (int sj = 0; sj < 4; ++sj)
        orow[sj * 16] = acc[i][sj][r] - biasr[i][r];
    }
}

// ---------------------------------------------------------------------------
extern "C" void kernel_launch(void* const* d_in, const int* in_sizes, int n_in,
                              void* d_out, int out_size, void* d_ws,
                              size_t ws_size, hipStream_t stream) {
  const float* x = (const float*)d_in[0];        // (64,128,56,56) fp32
  const float* rot = (const float*)d_in[1];      // (128,128) fp32
  float* out = (float*)d_out;                    // (64,128,56,56) fp32
  float* ws = (float*)d_ws;

  // ws layout (floats)
  float* Sigma  = ws;                        // 16384 (raw, eps included)
  float* Pa     = ws + 16384;                // 16384
  float* Pb     = ws + 32768;                // 16384
  unsigned short* Mbf = (unsigned short*)(ws + 49152);  // 16384 ushort
  float* Sb     = ws + 57344;                // 128 (mean)
  float* bias   = ws + 57472;                // 128
  float* traceP = ws + 57600;                // 16
  float* part2  = ws + 57616;                // 32*16384 = 524288
  float* part2S = ws + 57616 + 524288;       // 4096
  float* partG  = ws + 57616 + 524288 + 4096;

  const size_t wsf = ws_size / 4;
  long avail = (long)wsf - (57616 + 524288 + 4096);
  int slots = (int)(avail / (16384 + 128));
  if (slots > 448) slots = 448;   // 448 blocks = 2 chunks each; fills 2 blk/CU
  if (slots < 1) slots = 1;
  float* partS = partG + (size_t)slots * 16384;

  gram_k<<<slots, 512, 0, stream>>>(x, partG, partS, slots);
  reduce1_k<<<288, 256, 0, stream>>>(partG, partS, part2, part2S, slots);
  sigred_k<<<16, 256, 0, stream>>>(part2, part2S, Sigma, traceP, Sb);
  newton1_k<<<16, 256, 0, stream>>>(Sigma, traceP, Pb);         // -> P2
  newton_k<<<16, 256, 0, stream>>>(Pb, Sigma, traceP, Pa);      // -> P3
  newton_k<<<16, 256, 0, stream>>>(Pa, Sigma, traceP, Pb);      // -> P4
  newton_k<<<16, 256, 0, stream>>>(Pb, Sigma, traceP, Pa);      // -> P5
  rotmt_k<<<16, 256, 0, stream>>>(rot, Pa, Sb, traceP, Mbf, bias);
  apply_k<<<3136, 256, 0, stream>>>(x, Mbf, bias, out);
}

// Round 6
// 258.275 us; speedup vs baseline: 1.1563x; 1.1563x over previous
//
#include <hip/hip_runtime.h>
#include <math.h>

// Problem constants (B=64, C=128, H=W=56)
#define HW 3136
#define NCHUNK 3136          // 64 batches * 49 chunks of 64 samples
#define M_TOT 200704.0f
#define EPSV 1e-5f

typedef __attribute__((ext_vector_type(8))) short bf16x8;
typedef __attribute__((ext_vector_type(4))) short short4v;
typedef __attribute__((ext_vector_type(4))) float f32x4;

__device__ inline unsigned short f2bf(float f) {  // RNE fp32->bf16
  unsigned u = __float_as_uint(f);
  u += 0x7FFFu + ((u >> 16) & 1u);
  return (unsigned short)(u >> 16);
}

// ---------------------------------------------------------------------------
// Kernel 1: partial Gram (X @ X^T) + channel sums, bf16 MFMA 16x16x32.
// R0/R3 structure (verified 264-266us): chunk=64, slots=512, double-buffered
// LDS + 2-deep VGPR prefetch, ONE barrier/iter. 224-chunk variants (R4/R5)
// were +33us net despite 2.45 TB/s DRAM efficiency -- do not revisit.
// D layout (m89): col = lane&15, row = quad*4 + reg.
// ---------------------------------------------------------------------------
__global__ __launch_bounds__(512, 4) void gram_k(const float* __restrict__ x,
                                                 float* __restrict__ partG,
                                                 float* __restrict__ partS,
                                                 int slots) {
  __shared__ unsigned short xs[2][128 * 72];  // 2 x 18432 B
  const int t = threadIdx.x;
  const int lm = t & 15, quad = (t >> 4) & 3, w = t >> 6;  // w = 0..7
  const int row0 = w * 16;
  const int qofs = (t & 15) * 4;   // sample-quad offset for staging
  const int chi = t >> 4;          // 0..31 channel sub-index for staging

  f32x4 acc[8];
  f32x4 sacc;
  const f32x4 z = {0.f, 0.f, 0.f, 0.f};
  sacc = z;
#pragma unroll
  for (int j = 0; j < 8; ++j) acc[j] = z;
  bf16x8 ones;
#pragma unroll
  for (int j = 0; j < 8; ++j) ones[j] = (short)0x3F80;  // bf16 1.0

  int chunk = blockIdx.x;
  float4 pre0[4], pre1[4];
  {
    const int b = chunk / 49;
    const int s0 = (chunk % 49) * 64;
    const float* base = x + (size_t)(b * 128) * HW + s0;
#pragma unroll
    for (int i = 0; i < 4; ++i)
      pre0[i] = *(const float4*)(base + (size_t)(i * 32 + chi) * HW + qofs);
  }
  {
    const int n1 = chunk + slots;
    if (n1 < NCHUNK) {
      const int b = n1 / 49;
      const int s0 = (n1 % 49) * 64;
      const float* base = x + (size_t)(b * 128) * HW + s0;
#pragma unroll
      for (int i = 0; i < 4; ++i)
        pre1[i] = *(const float4*)(base + (size_t)(i * 32 + chi) * HW + qofs);
    }
  }

  int buf = 0;
  while (chunk < NCHUNK) {
    // stage pre0 (chunk) -> xs[buf]
#pragma unroll
    for (int i = 0; i < 4; ++i) {
      const int c = i * 32 + chi;
      uint2 dw;
      dw.x = (unsigned)f2bf(pre0[i].x) | ((unsigned)f2bf(pre0[i].y) << 16);
      dw.y = (unsigned)f2bf(pre0[i].z) | ((unsigned)f2bf(pre0[i].w) << 16);
      *(uint2*)&xs[buf][c * 72 + qofs] = dw;
    }
    __syncthreads();
    // rotate pipeline: pre0 <- pre1, issue pre1 <- chunk+2*slots
#pragma unroll
    for (int i = 0; i < 4; ++i) pre0[i] = pre1[i];
    {
      const int n2 = chunk + 2 * slots;
      if (n2 < NCHUNK) {
        const int b = n2 / 49;
        const int s0 = (n2 % 49) * 64;
        const float* base = x + (size_t)(b * 128) * HW + s0;
#pragma unroll
        for (int i = 0; i < 4; ++i)
          pre1[i] = *(const float4*)(base + (size_t)(i * 32 + chi) * HW + qofs);
      }
    }
    // compute from xs[buf]
#pragma unroll
    for (int ks = 0; ks < 2; ++ks) {
      const int ko = ks * 32 + quad * 8;
      const bf16x8 a0 = *(const bf16x8*)&xs[buf][(row0 + lm) * 72 + ko];
      sacc = __builtin_amdgcn_mfma_f32_16x16x32_bf16(a0, ones, sacc, 0, 0, 0);
#pragma unroll
      for (int tj = 0; tj < 8; ++tj) {
        const bf16x8 bf = *(const bf16x8*)&xs[buf][(tj * 16 + lm) * 72 + ko];
        acc[tj] = __builtin_amdgcn_mfma_f32_16x16x32_bf16(a0, bf, acc[tj], 0, 0, 0);
      }
    }
    buf ^= 1;
    chunk += slots;
  }

  float* pg = partG + (size_t)blockIdx.x * 16384;
#pragma unroll
  for (int tj = 0; tj < 8; ++tj)
#pragma unroll
    for (int r = 0; r < 4; ++r)
      pg[(row0 + quad * 4 + r) * 128 + tj * 16 + lm] = acc[tj][r];
  if (lm == 0) {
#pragma unroll
    for (int r = 0; r < 4; ++r)
      partS[blockIdx.x * 128 + row0 + quad * 4 + r] = sacc[r];
  }
}

// ---------------------------------------------------------------------------
// Kernel 2: stage-A reduction (32 slot-groups x 16 elem-groups = 512 blocks).
// ---------------------------------------------------------------------------
__global__ __launch_bounds__(256) void reduce1_k(const float* __restrict__ partG,
                                                 const float* __restrict__ partS,
                                                 float* __restrict__ part2,
                                                 float* __restrict__ part2S,
                                                 int slots) {
  const int t = threadIdx.x;
  const int sg = blockIdx.x & 31;
  const int eg = blockIdx.x >> 5;
  const int e4 = eg * 1024 + t * 4;
  float ax = 0.f, ay = 0.f, az = 0.f, aw = 0.f;
#pragma unroll 4
  for (int s = sg; s < slots; s += 32) {
    const float4 v = *(const float4*)(partG + (size_t)s * 16384 + e4);
    ax += v.x; ay += v.y; az += v.z; aw += v.w;
  }
  *(float4*)(part2 + (size_t)sg * 16384 + e4) = make_float4(ax, ay, az, aw);
  if (eg == 0 && t < 128) {
    float sa = 0.f;
    for (int s = sg; s < slots; s += 32) sa += partS[s * 128 + t];
    part2S[sg * 128 + t] = sa;
  }
}

// ---------------------------------------------------------------------------
// Kernel 3: merged stage-B reduce + Sigma build. grid = 16, block = 256.
// Raw Sigma = (G - S S^T/m)/m + eps*I (trace normalization deferred via
// traceP[0..15] partials).
// ---------------------------------------------------------------------------
__global__ __launch_bounds__(256) void sigred_k(const float* __restrict__ part2,
                                                const float* __restrict__ part2S,
                                                float* __restrict__ Sigma,
                                                float* __restrict__ traceP,
                                                float* __restrict__ meanOut) {
  __shared__ float SbL[128];
  __shared__ float red[256];
  const int t = threadIdx.x;
  if (t < 128) {
    float sa = 0.f;
#pragma unroll
    for (int sg = 0; sg < 32; ++sg) sa += part2S[sg * 128 + t];
    SbL[t] = sa;
    if (blockIdx.x == 0) meanOut[t] = sa * (1.0f / M_TOT);
  }
  __syncthreads();
  const int e4 = blockIdx.x * 1024 + t * 4;
  float ax = 0.f, ay = 0.f, az = 0.f, aw = 0.f;
#pragma unroll
  for (int sg = 0; sg < 32; ++sg) {
    const float4 v = *(const float4*)(part2 + (size_t)sg * 16384 + e4);
    ax += v.x; ay += v.y; az += v.z; aw += v.w;
  }
  const int r = e4 >> 7, c0 = e4 & 127;
  const float rm = 1.0f / M_TOT;
  const float sr = SbL[r] * rm;
  float s4[4];
  s4[0] = (ax - sr * SbL[c0 + 0]) * rm;
  s4[1] = (ay - sr * SbL[c0 + 1]) * rm;
  s4[2] = (az - sr * SbL[c0 + 2]) * rm;
  s4[3] = (aw - sr * SbL[c0 + 3]) * rm;
  float trl = 0.f;
#pragma unroll
  for (int j = 0; j < 4; ++j) {
    if (c0 + j == r) { s4[j] += EPSV; trl = s4[j]; }
  }
  *(float4*)(Sigma + e4) = make_float4(s4[0], s4[1], s4[2], s4[3]);
  red[t] = trl;
  __syncthreads();
  for (int off = 128; off > 0; off >>= 1) {
    if (t < off) red[t] += red[t + off];
    __syncthreads();
  }
  if (t == 0) traceP[blockIdx.x] = red[0];
}

// ---------------------------------------------------------------------------
// Kernel 4a: FIRST+SECOND Newton step fused (P1 = 1.5I - 0.5*rTr*Sigma
// synthesized; computes P2). ROUND-6: 32 blocks x 4 rows, 8-way k-split
// (16 iters/phase) -- halves each serial phase's k-chain and doubles the
// CUs/parallel L2 BW vs the 16-block version (mid-chain = the ~90us
// residual; each kernel is latency- not compute-bound).
// ---------------------------------------------------------------------------
__global__ __launch_bounds__(256) void newton1_k(const float* __restrict__ Sig,
                                                 const float* __restrict__ traceP,
                                                 float* __restrict__ Pout) {
  __shared__ float s1[4 * 132];
  __shared__ float s2[4 * 132];
  __shared__ float red[256 * 17];
  const int t = threadIdx.x;
  const int ct = t & 31;        // col tile (4 cols)
  const int kt = t >> 5;        // k eighth (0..7)
  const int k0 = kt * 16;
  const int rg0 = blockIdx.x * 4;
  float tr = 0.f;
#pragma unroll
  for (int i = 0; i < 16; ++i) tr += traceP[i];
  const float rTr = 1.0f / tr;
  const float nh = -0.5f * rTr;
  float a[4][4];

  // ---------- phase 1: s1 = strip(P1 @ P1) ----------
#pragma unroll
  for (int i = 0; i < 4; ++i)
#pragma unroll
    for (int j = 0; j < 4; ++j) a[i][j] = 0.f;
#pragma unroll 4
  for (int k = k0; k < k0 + 16; ++k) {
    const float4 sa4 = *(const float4*)(Sig + k * 128 + rg0);   // symmetry
    const float4 sb4 = *(const float4*)(Sig + k * 128 + 4 * ct);
    float aA[4] = {nh * sa4.x, nh * sa4.y, nh * sa4.z, nh * sa4.w};
    float bA[4] = {nh * sb4.x, nh * sb4.y, nh * sb4.z, nh * sb4.w};
#pragma unroll
    for (int i = 0; i < 4; ++i) if (rg0 + i == k) aA[i] += 1.5f;
#pragma unroll
    for (int j = 0; j < 4; ++j) if (4 * ct + j == k) bA[j] += 1.5f;
#pragma unroll
    for (int i = 0; i < 4; ++i)
#pragma unroll
      for (int j = 0; j < 4; ++j) a[i][j] += aA[i] * bA[j];
  }
#pragma unroll
  for (int i = 0; i < 4; ++i)
#pragma unroll
    for (int j = 0; j < 4; ++j) red[t * 17 + i * 4 + j] = a[i][j];
  __syncthreads();
  if (t < 32) {
#pragma unroll
    for (int u = 1; u < 8; ++u)
#pragma unroll
      for (int i = 0; i < 4; ++i)
#pragma unroll
        for (int j = 0; j < 4; ++j)
          a[i][j] += red[(t + 32 * u) * 17 + i * 4 + j];
#pragma unroll
    for (int i = 0; i < 4; ++i)
#pragma unroll
      for (int j = 0; j < 4; ++j)
        s1[i * 132 + 4 * ct + j] = a[i][j];
  }
  __syncthreads();

  // ---------- phase 2: s2 = s1 @ P1 ----------
#pragma unroll
  for (int i = 0; i < 4; ++i)
#pragma unroll
    for (int j = 0; j < 4; ++j) a[i][j] = 0.f;
#pragma unroll 4
  for (int k = k0; k < k0 + 16; ++k) {
    float aA[4];
#pragma unroll
    for (int i = 0; i < 4; ++i) aA[i] = s1[i * 132 + k];
    const float4 sb4 = *(const float4*)(Sig + k * 128 + 4 * ct);
    float bA[4] = {nh * sb4.x, nh * sb4.y, nh * sb4.z, nh * sb4.w};
#pragma unroll
    for (int j = 0; j < 4; ++j) if (4 * ct + j == k) bA[j] += 1.5f;
#pragma unroll
    for (int i = 0; i < 4; ++i)
#pragma unroll
      for (int j = 0; j < 4; ++j) a[i][j] += aA[i] * bA[j];
  }
  __syncthreads();
#pragma unroll
  for (int i = 0; i < 4; ++i)
#pragma unroll
    for (int j = 0; j < 4; ++j) red[t * 17 + i * 4 + j] = a[i][j];
  __syncthreads();
  if (t < 32) {
#pragma unroll
    for (int u = 1; u < 8; ++u)
#pragma unroll
      for (int i = 0; i < 4; ++i)
#pragma unroll
        for (int j = 0; j < 4; ++j)
          a[i][j] += red[(t + 32 * u) * 17 + i * 4 + j];
#pragma unroll
    for (int i = 0; i < 4; ++i)
#pragma unroll
      for (int j = 0; j < 4; ++j)
        s2[i * 132 + 4 * ct + j] = a[i][j];
  }
  __syncthreads();

  // ---------- phase 3: a = s2 @ Sigma_raw; Pout = 0.5*(3 P1 - rTr*a) ----------
#pragma unroll
  for (int i = 0; i < 4; ++i)
#pragma unroll
    for (int j = 0; j < 4; ++j) a[i][j] = 0.f;
#pragma unroll 4
  for (int k = k0; k < k0 + 16; ++k) {
    float aA[4];
#pragma unroll
    for (int i = 0; i < 4; ++i) aA[i] = s2[i * 132 + k];
    const float4 bv = *(const float4*)(Sig + k * 128 + 4 * ct);
    const float bA[4] = {bv.x, bv.y, bv.z, bv.w};
#pragma unroll
    for (int i = 0; i < 4; ++i)
#pragma unroll
      for (int j = 0; j < 4; ++j) a[i][j] += aA[i] * bA[j];
  }
  __syncthreads();
#pragma unroll
  for (int i = 0; i < 4; ++i)
#pragma unroll
    for (int j = 0; j < 4; ++j) red[t * 17 + i * 4 + j] = a[i][j];
  __syncthreads();
  if (t < 32) {
#pragma unroll
    for (int u = 1; u < 8; ++u)
#pragma unroll
      for (int i = 0; i < 4; ++i)
#pragma unroll
        for (int j = 0; j < 4; ++j)
          a[i][j] += red[(t + 32 * u) * 17 + i * 4 + j];
#pragma unroll
    for (int i = 0; i < 4; ++i) {
      const int rg = rg0 + i;
      const float4 sv = *(const float4*)(Sig + rg * 128 + 4 * ct);
      float p1v[4] = {nh * sv.x, nh * sv.y, nh * sv.z, nh * sv.w};
#pragma unroll
      for (int j = 0; j < 4; ++j) if (4 * ct + j == rg) p1v[j] += 1.5f;
      *(float4*)(Pout + rg * 128 + 4 * ct) =
          make_float4(0.5f * (3.f * p1v[0] - rTr * a[i][0]),
                      0.5f * (3.f * p1v[1] - rTr * a[i][1]),
                      0.5f * (3.f * p1v[2] - rTr * a[i][2]),
                      0.5f * (3.f * p1v[3] - rTr * a[i][3]));
    }
  }
}

// ---------------------------------------------------------------------------
// Kernel 4b: one Newton iteration: Pout = 0.5*(3P - ((P@P)@P)@(rTr*Sigma)).
// ROUND-6: 32 blocks x 4 rows, 8-way k-split (16 iters/phase).
// ---------------------------------------------------------------------------
__global__ __launch_bounds__(256) void newton_k(const float* __restrict__ P,
                                                const float* __restrict__ Sig,
                                                const float* __restrict__ traceP,
                                                float* __restrict__ Pout) {
  __shared__ float s1[4 * 132];
  __shared__ float s2[4 * 132];
  __shared__ float red[256 * 17];
  const int t = threadIdx.x;
  const int ct = t & 31;
  const int kt = t >> 5;
  const int k0 = kt * 16;
  const int rg0 = blockIdx.x * 4;
  float tr = 0.f;
#pragma unroll
  for (int i = 0; i < 16; ++i) tr += traceP[i];
  const float rTr = 1.0f / tr;
  float a[4][4];

  // ---------- phase 1: s1 = strip(P @ P) ----------
#pragma unroll
  for (int i = 0; i < 4; ++i)
#pragma unroll
    for (int j = 0; j < 4; ++j) a[i][j] = 0.f;
#pragma unroll 4
  for (int k = k0; k < k0 + 16; ++k) {
    const float4 av = *(const float4*)(P + k * 128 + rg0);  // symmetry
    const float4 bv = *(const float4*)(P + k * 128 + 4 * ct);
    const float aA[4] = {av.x, av.y, av.z, av.w};
    const float bA[4] = {bv.x, bv.y, bv.z, bv.w};
#pragma unroll
    for (int i = 0; i < 4; ++i)
#pragma unroll
      for (int j = 0; j < 4; ++j) a[i][j] += aA[i] * bA[j];
  }
#pragma unroll
  for (int i = 0; i < 4; ++i)
#pragma unroll
    for (int j = 0; j < 4; ++j) red[t * 17 + i * 4 + j] = a[i][j];
  __syncthreads();
  if (t < 32) {
#pragma unroll
    for (int u = 1; u < 8; ++u)
#pragma unroll
      for (int i = 0; i < 4; ++i)
#pragma unroll
        for (int j = 0; j < 4; ++j)
          a[i][j] += red[(t + 32 * u) * 17 + i * 4 + j];
#pragma unroll
    for (int i = 0; i < 4; ++i)
#pragma unroll
      for (int j = 0; j < 4; ++j)
        s1[i * 132 + 4 * ct + j] = a[i][j];
  }
  __syncthreads();

  // ---------- phase 2: s2 = s1 @ P ----------
#pragma unroll
  for (int i = 0; i < 4; ++i)
#pragma unroll
    for (int j = 0; j < 4; ++j) a[i][j] = 0.f;
#pragma unroll 4
  for (int k = k0; k < k0 + 16; ++k) {
    float aA[4];
#pragma unroll
    for (int i = 0; i < 4; ++i) aA[i] = s1[i * 132 + k];
    const float4 bv = *(const float4*)(P + k * 128 + 4 * ct);
    const float bA[4] = {bv.x, bv.y, bv.z, bv.w};
#pragma unroll
    for (int i = 0; i < 4; ++i)
#pragma unroll
      for (int j = 0; j < 4; ++j) a[i][j] += aA[i] * bA[j];
  }
  __syncthreads();
#pragma unroll
  for (int i = 0; i < 4; ++i)
#pragma unroll
    for (int j = 0; j < 4; ++j) red[t * 17 + i * 4 + j] = a[i][j];
  __syncthreads();
  if (t < 32) {
#pragma unroll
    for (int u = 1; u < 8; ++u)
#pragma unroll
      for (int i = 0; i < 4; ++i)
#pragma unroll
        for (int j = 0; j < 4; ++j)
          a[i][j] += red[(t + 32 * u) * 17 + i * 4 + j];
#pragma unroll
    for (int i = 0; i < 4; ++i)
#pragma unroll
      for (int j = 0; j < 4; ++j)
        s2[i * 132 + 4 * ct + j] = a[i][j];
  }
  __syncthreads();

  // ---------- phase 3: a = s2 @ Sigma_raw; Pout = 0.5*(3P - rTr*a) ----------
#pragma unroll
  for (int i = 0; i < 4; ++i)
#pragma unroll
    for (int j = 0; j < 4; ++j) a[i][j] = 0.f;
#pragma unroll 4
  for (int k = k0; k < k0 + 16; ++k) {
    float aA[4];
#pragma unroll
    for (int i = 0; i < 4; ++i) aA[i] = s2[i * 132 + k];
    const float4 bv = *(const float4*)(Sig + k * 128 + 4 * ct);
    const float bA[4] = {bv.x, bv.y, bv.z, bv.w};
#pragma unroll
    for (int i = 0; i < 4; ++i)
#pragma unroll
      for (int j = 0; j < 4; ++j) a[i][j] += aA[i] * bA[j];
  }
  __syncthreads();
#pragma unroll
  for (int i = 0; i < 4; ++i)
#pragma unroll
    for (int j = 0; j < 4; ++j) red[t * 17 + i * 4 + j] = a[i][j];
  __syncthreads();
  if (t < 32) {
#pragma unroll
    for (int u = 1; u < 8; ++u)
#pragma unroll
      for (int i = 0; i < 4; ++i)
#pragma unroll
        for (int j = 0; j < 4; ++j)
          a[i][j] += red[(t + 32 * u) * 17 + i * 4 + j];
#pragma unroll
    for (int i = 0; i < 4; ++i) {
      const int rg = rg0 + i;
      const float4 pv = *(const float4*)(P + rg * 128 + 4 * ct);
      *(float4*)(Pout + rg * 128 + 4 * ct) =
          make_float4(0.5f * (3.f * pv.x - rTr * a[i][0]),
                      0.5f * (3.f * pv.y - rTr * a[i][1]),
                      0.5f * (3.f * pv.z - rTr * a[i][2]),
                      0.5f * (3.f * pv.w - rTr * a[i][3]));
    }
  }
}

// ---------------------------------------------------------------------------
// Kernel 5: Mbf = bf16(sqrt(rTr) * rot @ P) row-major [d][c];
// bias[d] = sum_c M[d][c]*mean[c]. grid = 16, block = 256.
// ---------------------------------------------------------------------------
__global__ __launch_bounds__(256) void rotmt_k(const float* __restrict__ rot,
                                               const float* __restrict__ P,
                                               const float* __restrict__ mean,
                                               const float* __restrict__ traceP,
                                               unsigned short* __restrict__ Mbf,
                                               float* __restrict__ bias) {
  const int t = threadIdx.x;
  const int r = t >> 5;
  const int dg = blockIdx.x * 8 + r;
  const int c0 = (t & 31) * 4;
  const float* rrow = rot + dg * 128;
  float tr = 0.f;
#pragma unroll
  for (int i = 0; i < 16; ++i) tr += traceP[i];
  const float sc = sqrtf(1.0f / tr);

  float ax = 0, ay = 0, az = 0, aw = 0;
#pragma unroll 4
  for (int k = 0; k < 128; ++k) {
    const float a = rrow[k];
    const float4 bv = *(const float4*)(P + k * 128 + c0);
    ax += a * bv.x; ay += a * bv.y; az += a * bv.z; aw += a * bv.w;
  }
  ax *= sc; ay *= sc; az *= sc; aw *= sc;
  uint2 dw;
  dw.x = (unsigned)f2bf(ax) | ((unsigned)f2bf(ay) << 16);
  dw.y = (unsigned)f2bf(az) | ((unsigned)f2bf(aw) << 16);
  *(uint2*)&Mbf[dg * 128 + c0] = dw;
  const float4 mv = *(const float4*)(mean + c0);
  float p = ax * mv.x + ay * mv.y + az * mv.z + aw * mv.w;
  for (int off = 16; off > 0; off >>= 1) p += __shfl_down(p, off, 32);
  if ((t & 31) == 0) bias[dg] = p;
}

// ---------------------------------------------------------------------------
// Kernel 6: out[b,d,s] = sum_c M[d][c]*x[c,s] - bias[d], bf16 MFMA.
// grid = 3136, block = 256 (4 waves), 3 blocks/CU (LDS 51.7KB x3 = 155KB).
// ---------------------------------------------------------------------------
#define MSTR 136
#define XSTR 132
__global__ __launch_bounds__(256, 3) void apply_k(const float* __restrict__ x,
                                                  const unsigned short* __restrict__ Mbf,
                                                  const float* __restrict__ bias,
                                                  float* __restrict__ out) {
  __shared__ unsigned short Ms[128 * MSTR];   // 34816 B
  __shared__ unsigned short xsB[64 * XSTR];   // 16896 B
  const int t = threadIdx.x;
  const int lm = t & 15, quad = (t >> 4) & 3, w = t >> 6;
  const int b = blockIdx.x / 49;
  const int s0 = (blockIdx.x % 49) * 64;

  // stage M (L2-hot) -- independent of x loads, overlaps them
#pragma unroll
  for (int i = 0; i < 8; ++i) {
    const int e = i * 256 + t;
    const int row = e >> 4, oct = e & 15;
    *(uint4*)&Ms[row * MSTR + oct * 8] =
        *(const uint4*)(Mbf + row * 128 + oct * 8);
  }
  // stage x chunk transposed: pair p -> channels {2p, 2p+1}
#pragma unroll
  for (int i = 0; i < 4; ++i) {
    const int p = 16 * i + (t >> 4);
    const int q = t & 15;
    const float* px = x + (size_t)(b * 128 + 2 * p) * HW + s0 + 4 * q;
    const float4 fa = *(const float4*)px;
    const float4 fb = *(const float4*)(px + HW);
    const float faA[4] = {fa.x, fa.y, fa.z, fa.w};
    const float fbA[4] = {fb.x, fb.y, fb.z, fb.w};
#pragma unroll
    for (int r = 0; r < 4; ++r) {
      const unsigned dw =
          (unsigned)f2bf(faA[r]) | ((unsigned)f2bf(fbA[r]) << 16);
      *(unsigned*)&xsB[(4 * q + r) * XSTR + 2 * p] = dw;
    }
  }
  float biasr[2][4];
#pragma unroll
  for (int i = 0; i < 2; ++i)
#pragma unroll
    for (int r = 0; r < 4; ++r)
      biasr[i][r] = bias[(2 * w + i) * 16 + quad * 4 + r];
  __syncthreads();

  const f32x4 z = {0.f, 0.f, 0.f, 0.f};
  f32x4 acc[2][4];
#pragma unroll
  for (int i = 0; i < 2; ++i)
#pragma unroll
    for (int sj = 0; sj < 4; ++sj) acc[i][sj] = z;

#pragma unroll
  for (int ks = 0; ks < 4; ++ks) {
    const int ko = ks * 32 + quad * 8;
    const bf16x8 a0 = *(const bf16x8*)&Ms[((2 * w + 0) * 16 + lm) * MSTR + ko];
    const bf16x8 a1 = *(const bf16x8*)&Ms[((2 * w + 1) * 16 + lm) * MSTR + ko];
#pragma unroll
    for (int sj = 0; sj < 4; ++sj) {
      const short4v blo = *(const short4v*)&xsB[(sj * 16 + lm) * XSTR + ko];
      const short4v bhi = *(const short4v*)&xsB[(sj * 16 + lm) * XSTR + ko + 4];
      const bf16x8 bf = __builtin_shufflevector(blo, bhi, 0, 1, 2, 3, 4, 5, 6, 7);
      acc[0][sj] = __builtin_amdgcn_mfma_f32_16x16x32_bf16(a0, bf, acc[0][sj], 0, 0, 0);
      acc[1][sj] = __builtin_amdgcn_mfma_f32_16x16x32_bf16(a1, bf, acc[1][sj], 0, 0, 0);
    }
  }
  // epilogue: D col = lane&15 = s, row = quad*4+reg = d-within-tile
#pragma unroll
  for (int i = 0; i < 2; ++i)
#pragma unroll
    for (int r = 0; r < 4; ++r) {
      const int d = (2 * w + i) * 16 + quad * 4 + r;
      float* orow = out + (size_t)(b * 128 + d) * HW + s0 + lm;
#pragma unroll
      for (int sj = 0; sj < 4; ++sj)
        orow[sj * 16] = acc[i][sj][r] - biasr[i][r];
    }
}

// ---------------------------------------------------------------------------
extern "C" void kernel_launch(void* const* d_in, const int* in_sizes, int n_in,
                              void* d_out, int out_size, void* d_ws,
                              size_t ws_size, hipStream_t stream) {
  const float* x = (const float*)d_in[0];        // (64,128,56,56) fp32
  const float* rot = (const float*)d_in[1];      // (128,128) fp32
  float* out = (float*)d_out;                    // (64,128,56,56) fp32
  float* ws = (float*)d_ws;

  // ws layout (floats)
  float* Sigma  = ws;                        // 16384 (raw, eps included)
  float* Pa     = ws + 16384;                // 16384
  float* Pb     = ws + 32768;                // 16384
  unsigned short* Mbf = (unsigned short*)(ws + 49152);  // 16384 ushort
  float* Sb     = ws + 57344;                // 128 (mean)
  float* bias   = ws + 57472;                // 128
  float* traceP = ws + 57600;                // 16
  float* part2  = ws + 57616;                // 32*16384 = 524288
  float* part2S = ws + 57616 + 524288;       // 4096
  float* partG  = ws + 57616 + 524288 + 4096;

  const size_t wsf = ws_size / 4;
  long avail = (long)wsf - (57616 + 524288 + 4096);
  int slots = (int)(avail / (16384 + 128));
  if (slots > 512) slots = 512;
  if (slots < 1) slots = 1;
  float* partS = partG + (size_t)slots * 16384;

  gram_k<<<slots, 512, 0, stream>>>(x, partG, partS, slots);
  reduce1_k<<<512, 256, 0, stream>>>(partG, partS, part2, part2S, slots);
  sigred_k<<<16, 256, 0, stream>>>(part2, part2S, Sigma, traceP, Sb);
  newton1_k<<<32, 256, 0, stream>>>(Sigma, traceP, Pb);         // -> P2
  newton_k<<<32, 256, 0, stream>>>(Pb, Sigma, traceP, Pa);      // -> P3
  newton_k<<<32, 256, 0, stream>>>(Pa, Sigma, traceP, Pb);      // -> P4
  newton_k<<<32, 256, 0, stream>>>(Pb, Sigma, traceP, Pa);      // -> P5
  rotmt_k<<<16, 256, 0, stream>>>(rot, Pa, Sb, traceP, Mbf, bias);
  apply_k<<<3136, 256, 0, stream>>>(x, Mbf, bias, out);
}